// Round 3
// baseline (181.285 us; speedup 1.0000x reference)
//
#include <hip/hip_runtime.h>

// B=128, K=256, M=8, D=128 ; rows = B*K = 32768 flattened (b,k)
#define NROWS 32768
#define LT 20.0f        // lambda == gamma == 20
#define CHUNKS 16       // 16 chunks x 64 cols = 1024 cols per block (one column half)

typedef _Float16 half8 __attribute__((ext_vector_type(8)));
typedef float    f32x4 __attribute__((ext_vector_type(4)));

__device__ __forceinline__ float swz16(float x) {
    // xor lane^16 within 32-lane halves (BitMode: xor=16, and=0x1F)
    return __int_as_float(__builtin_amdgcn_ds_swizzle(__float_as_int(x), 0x401F));
}

// Grid: 512 blocks = 256 row-blocks x 2 column-halves. Block: 512 thr = 8 waves.
// wave w: half=w>>2 -> 64 rows, colq=w&3 -> 16-col quarter of each 64-col chunk.
// MFMA 16x16x32 f16: A = P (16 cols = 2 concepts x 8 protos), B = V (16 rows).
__global__ __launch_bounds__(512, 4)
void mpcl_main(const float* __restrict__ V,       // (32768, 128)
               const int*   __restrict__ labels,  // (32768)
               const float* __restrict__ P,       // (2048, 128) [concept*8+m][d]
               int* __restrict__ ws,              // see layout below
               float* __restrict__ out)
{
    __shared__ _Float16 Pst[2][64 * 128];   // 2 x 16 KB double buffer, XOR-swizzled
    __shared__ float sh_denom[128];
    __shared__ float sh_simpos[128];
    __shared__ float sh_red[16];
    __shared__ int   sh_flag;

    // ws layout: [0..255]=per-rowblk arrival cnt, [256]=global cnt, [258..259]=f32 sums,
    // [512..]=wsd[2][32768] denom halves, then wsp[32768] simpos. memset covers first 2048 B.
    int*   cnt  = ws;
    int*   gcnt = ws + 256;
    float* gsum = (float*)(ws + 258);
    float* wsd  = (float*)(ws + 512);
    float* wsp  = wsd + 2 * 32768;

    const int tid  = threadIdx.x;
    const int lane = tid & 63;
    const int w    = tid >> 6;
    const int half = w >> 2;
    const int colq = w & 3;
    const int n    = lane & 15;
    const int q    = lane >> 4;
    const int rowblk  = blockIdx.x >> 1;
    const int colhalf = blockIdx.x & 1;
    const int rowbase = rowblk * 128;
    const int cb   = colq * 16;

    if (tid < 128) sh_denom[tid] = 0.0f;

    // ---- V fragments (B operand), single f16 round, register-resident (64 VGPR) ----
    half8 vh[4][4];
#pragma unroll
    for (int rf = 0; rf < 4; ++rf) {
        const float* vr = V + (size_t)(rowbase + half * 64 + rf * 16 + n) * 128 + q * 8;
#pragma unroll
        for (int c = 0; c < 4; ++c) {
            float4 x0 = *(const float4*)(vr + c * 32);
            float4 x1 = *(const float4*)(vr + c * 32 + 4);
            vh[rf][c][0] = (_Float16)x0.x; vh[rf][c][1] = (_Float16)x0.y;
            vh[rf][c][2] = (_Float16)x0.z; vh[rf][c][3] = (_Float16)x0.w;
            vh[rf][c][4] = (_Float16)x1.x; vh[rf][c][5] = (_Float16)x1.y;
            vh[rf][c][6] = (_Float16)x1.z; vh[rf][c][7] = (_Float16)x1.w;
        }
    }

    // ---- staging indices: thread covers 2 dblks (16 d) of one col ----
    const int scol = tid >> 3;        // 0..63
    const int sdb  = (tid & 7) * 2;   // dblk base (dblk = d/8)
    const float* Pb = P + (size_t)colhalf * 1024 * 128;

    // stage chunk 0 directly
    {
        const float* pp = Pb + (size_t)scol * 128 + sdb * 8;
#pragma unroll
        for (int p = 0; p < 2; ++p) {
            float4 a = *(const float4*)(pp + p * 8);
            float4 b = *(const float4*)(pp + p * 8 + 4);
            int dblk = sdb + p;
            int dbs  = (dblk & 8) | ((dblk ^ scol) & 7);
            half8 hv;
            hv[0] = (_Float16)a.x; hv[1] = (_Float16)a.y;
            hv[2] = (_Float16)a.z; hv[3] = (_Float16)a.w;
            hv[4] = (_Float16)b.x; hv[5] = (_Float16)b.y;
            hv[6] = (_Float16)b.z; hv[7] = (_Float16)b.w;
            *(half8*)&Pst[0][scol * 128 + dbs * 8] = hv;
        }
    }
    // prefetch chunk 1 into registers
    float4 pf[4];
    {
        const float* pp = Pb + (size_t)(64 + scol) * 128 + sdb * 8;
        pf[0] = *(const float4*)(pp);      pf[1] = *(const float4*)(pp + 4);
        pf[2] = *(const float4*)(pp + 8);  pf[3] = *(const float4*)(pp + 12);
    }

    float dn[4] = {0.f, 0.f, 0.f, 0.f};

#pragma unroll 1
    for (int ch = 0; ch < CHUNKS; ++ch) {
        __syncthreads();   // staged buffer ch&1 ready; buffer (ch+1)&1 free for writing

        // P fragments (A operand) from current buffer
        half8 pf16[4];
#pragma unroll
        for (int c = 0; c < 4; ++c) {
            int dblk = c * 4 + q;
            int col  = cb + n;
            int dbs  = (dblk & 8) | ((dblk ^ col) & 7);
            pf16[c] = *(const half8*)&Pst[ch & 1][col * 128 + dbs * 8];
        }

        f32x4 acc[4] = {{0.f,0.f,0.f,0.f},{0.f,0.f,0.f,0.f},
                        {0.f,0.f,0.f,0.f},{0.f,0.f,0.f,0.f}};
#pragma unroll
        for (int c = 0; c < 4; ++c)
#pragma unroll
            for (int rf = 0; rf < 4; ++rf)
                acc[rf] = __builtin_amdgcn_mfma_f32_16x16x32_f16(pf16[c], vh[rf][c], acc[rf], 0, 0, 0);

        // stage next chunk into the other buffer (pf loaded a full chunk ago)
        if (ch < CHUNKS - 1) {
#pragma unroll
            for (int p = 0; p < 2; ++p) {
                int dblk = sdb + p;
                int dbs  = (dblk & 8) | ((dblk ^ scol) & 7);
                float4 a = pf[2 * p], b = pf[2 * p + 1];
                half8 hv;
                hv[0] = (_Float16)a.x; hv[1] = (_Float16)a.y;
                hv[2] = (_Float16)a.z; hv[3] = (_Float16)a.w;
                hv[4] = (_Float16)b.x; hv[5] = (_Float16)b.y;
                hv[6] = (_Float16)b.z; hv[7] = (_Float16)b.w;
                *(half8*)&Pst[(ch + 1) & 1][scol * 128 + dbs * 8] = hv;
            }
        }
        if (ch < CHUNKS - 2) {
            const float* pp = Pb + (size_t)((ch + 2) * 64 + scol) * 128 + sdb * 8;
            pf[0] = *(const float4*)(pp);      pf[1] = *(const float4*)(pp + 4);
            pf[2] = *(const float4*)(pp + 8);  pf[3] = *(const float4*)(pp + 12);
        }

        // ---- epilogue: softmax over m (4 in-lane + xor16), logsumexp partials ----
        const int cbase = colhalf * 128 + ch * 8 + colq * 2;
        const int cA    = cbase + (q >> 1);
#pragma unroll
        for (int rf = 0; rf < 4; ++rf) {
            float s0 = acc[rf][0], s1 = acc[rf][1], s2 = acc[rf][2], s3 = acc[rf][3];
            float e0 = __expf(LT * s0), e1 = __expf(LT * s1);
            float e2 = __expf(LT * s2), e3 = __expf(LT * s3);
            float es = (e0 + e1) + (e2 + e3);
            float ss = fmaf(e0, s0, fmaf(e1, s1, fmaf(e2, s2, e3 * s3)));
            es += swz16(es);
            ss += swz16(ss);
            float simc = __fdividef(ss, es);
            dn[rf] += __expf(LT * simc);
            int rowloc = half * 64 + rf * 16 + n;
            if (cA == ((rowbase + rowloc) & 255) && (q & 1) == 0)
                sh_simpos[rowloc] = simc;
        }
    }

    // ---- fold per-lane denominators (q pairs duplicate concepts -> x0.5) ----
#pragma unroll
    for (int rf = 0; rf < 4; ++rf) {
        float t = dn[rf];
        t += swz16(t);
        t += __shfl_xor(t, 32);
        if (q == 0)
            atomicAdd(&sh_denom[half * 64 + rf * 16 + n], 0.5f * t);
    }
    __syncthreads();

    // ---- publish per-row partials ----
    if (tid < 128) {
        int row = rowbase + tid;
        __hip_atomic_store(&wsd[colhalf * 32768 + row], sh_denom[tid],
                           __ATOMIC_RELAXED, __HIP_MEMORY_SCOPE_AGENT);
        if (colhalf == (rowblk & 1))   // positive concepts of these rows live in this half
            __hip_atomic_store(&wsp[row], sh_simpos[tid],
                               __ATOMIC_RELAXED, __HIP_MEMORY_SCOPE_AGENT);
    }
    __syncthreads();
    if (tid == 0) {
        __threadfence();
        sh_flag = __hip_atomic_fetch_add(&cnt[rowblk], 1,
                                         __ATOMIC_ACQ_REL, __HIP_MEMORY_SCOPE_AGENT);
    }
    __syncthreads();

    // ---- second arriver of the pair computes the 128 row losses ----
    if (sh_flag == 1) {
        __threadfence();
        float s = 0.f, c = 0.f;
        if (tid < 128) {
            int row = rowbase + tid;
            float d0 = __hip_atomic_load(&wsd[row],         __ATOMIC_RELAXED, __HIP_MEMORY_SCOPE_AGENT);
            float d1 = __hip_atomic_load(&wsd[32768 + row], __ATOMIC_RELAXED, __HIP_MEMORY_SCOPE_AGENT);
            float sp = __hip_atomic_load(&wsp[row],         __ATOMIC_RELAXED, __HIP_MEMORY_SCOPE_AGENT);
            float lp = logf(d0 + d1 + 1e-8f) - LT * (sp + 0.05f);
            float mk = (labels[row] == 1) ? 1.0f : 0.0f;
            s = lp * mk;
            c = mk;
        }
#pragma unroll
        for (int off = 32; off >= 1; off >>= 1) {
            s += __shfl_down(s, off);
            c += __shfl_down(c, off);
        }
        if (lane == 0) { sh_red[w] = s; sh_red[8 + w] = c; }
        __syncthreads();
        if (tid == 0) {
            s = 0.f; c = 0.f;
#pragma unroll
            for (int i = 0; i < 8; ++i) { s += sh_red[i]; c += sh_red[8 + i]; }
            atomicAdd(&gsum[0], s);
            atomicAdd(&gsum[1], c);
            __threadfence();
            int g = __hip_atomic_fetch_add(gcnt, 1,
                                           __ATOMIC_ACQ_REL, __HIP_MEMORY_SCOPE_AGENT);
            if (g == 255) {   // last of the 256 finalizing blocks
                __threadfence();
                float ts = __hip_atomic_load(&gsum[0], __ATOMIC_RELAXED, __HIP_MEMORY_SCOPE_AGENT);
                float tc = __hip_atomic_load(&gsum[1], __ATOMIC_RELAXED, __HIP_MEMORY_SCOPE_AGENT);
                out[0] = (tc > 0.0f) ? (ts / tc) : ts;
            }
        }
    }
}

extern "C" void kernel_launch(void* const* d_in, const int* in_sizes, int n_in,
                              void* d_out, int out_size, void* d_ws, size_t ws_size,
                              hipStream_t stream)
{
    const float* V      = (const float*)d_in[0];
    const int*   labels = (const int*)d_in[1];
    const float* P      = (const float*)d_in[2];
    float* out = (float*)d_out;
    int*   ws  = (int*)d_ws;

    // zero counters + scalar accumulators (first 2048 B of ws)
    hipMemsetAsync(ws, 0, 2048, stream);
    mpcl_main<<<512, 512, 0, stream>>>(V, labels, P, ws, out);
}

// Round 4
// 115.492 us; speedup vs baseline: 1.5697x; 1.5697x over previous
//
#include <hip/hip_runtime.h>

// B=128, K=256, M=8, D=128 ; rows = B*K = 32768 flattened (b,k)
#define NROWS 32768
#define LT 20.0f        // lambda == gamma == 20
#define CHUNKS 32       // 32 chunks x 64 cols = all 2048 prototype columns

typedef _Float16 half8 __attribute__((ext_vector_type(8)));
typedef float    f32x4 __attribute__((ext_vector_type(4)));

__device__ __forceinline__ float swz16(float x) {
    // xor lane^16 within 32-lane halves (BitMode: xor=16, and=0x1F)
    return __int_as_float(__builtin_amdgcn_ds_swizzle(__float_as_int(x), 0x401F));
}

// Grid: 256 blocks x 1024 threads (16 waves). Block owns 128 rows x all 2048 cols.
// 1024-thr block => 4 waves/SIMD structurally => compiler VGPR cap 128 (no spill at ~90 demand).
// wave w: rg=w>>2 -> rows rg*32..+31 ; colq=w&3 -> 16-col quarter of each 64-col chunk.
// MFMA 16x16x32 f16: A = P (16 cols = 2 concepts x 8 protos), B = V (16 rows).
__global__ __launch_bounds__(1024)
void mpcl_main(const float* __restrict__ V,       // (32768, 128)
               const int*   __restrict__ labels,  // (32768)
               const float* __restrict__ P,       // (2048, 128) [concept*8+m][d]
               int* __restrict__ ws,              // [0]=gcnt, [2..3]=gsum
               float* __restrict__ out)
{
    __shared__ _Float16 Pst[2][64 * 128];   // 2 x 16 KB double buffer, XOR-swizzled
    __shared__ float sh_denom[128];
    __shared__ float sh_simpos[128];
    __shared__ float sh_red[32];

    int*   gcnt = ws;
    float* gsum = (float*)(ws + 2);

    const int tid  = threadIdx.x;
    const int lane = tid & 63;
    const int w    = tid >> 6;
    const int rg   = w >> 2;          // 0..3 -> 32-row group
    const int colq = w & 3;           // 0..3 -> 16-col quarter of chunk
    const int n    = lane & 15;
    const int q    = lane >> 4;
    const int rowbase = blockIdx.x * 128;
    const int cb   = colq * 16;

    if (tid < 128) { sh_denom[tid] = 0.0f; sh_simpos[tid] = 0.0f; }

    // ---- V fragments (B operand), f16, register-resident: 32 VGPRs ----
    half8 vh[2][4];
#pragma unroll
    for (int rf = 0; rf < 2; ++rf) {
        const float* vr = V + (size_t)(rowbase + rg * 32 + rf * 16 + n) * 128 + q * 8;
#pragma unroll
        for (int c = 0; c < 4; ++c) {
            float4 x0 = *(const float4*)(vr + c * 32);
            float4 x1 = *(const float4*)(vr + c * 32 + 4);
            vh[rf][c][0] = (_Float16)x0.x; vh[rf][c][1] = (_Float16)x0.y;
            vh[rf][c][2] = (_Float16)x0.z; vh[rf][c][3] = (_Float16)x0.w;
            vh[rf][c][4] = (_Float16)x1.x; vh[rf][c][5] = (_Float16)x1.y;
            vh[rf][c][6] = (_Float16)x1.z; vh[rf][c][7] = (_Float16)x1.w;
        }
    }

    // ---- staging: each of 1024 threads covers 1 dblk (8 d) of one col ----
    const int scol = tid >> 4;        // 0..63
    const int sdb  = tid & 15;        // dblk 0..15
    const int sdbs = (sdb & 8) | ((sdb ^ scol) & 7);   // swizzled dblk

    // stage chunk 0 directly
    {
        const float* pp = P + (size_t)scol * 128 + sdb * 8;
        float4 a = *(const float4*)(pp);
        float4 b = *(const float4*)(pp + 4);
        half8 hv;
        hv[0] = (_Float16)a.x; hv[1] = (_Float16)a.y;
        hv[2] = (_Float16)a.z; hv[3] = (_Float16)a.w;
        hv[4] = (_Float16)b.x; hv[5] = (_Float16)b.y;
        hv[6] = (_Float16)b.z; hv[7] = (_Float16)b.w;
        *(half8*)&Pst[0][scol * 128 + sdbs * 8] = hv;
    }
    // prefetch chunk 1 into registers
    float4 pf0, pf1;
    {
        const float* pp = P + (size_t)(64 + scol) * 128 + sdb * 8;
        pf0 = *(const float4*)(pp);
        pf1 = *(const float4*)(pp + 4);
    }

    float dn[2] = {0.f, 0.f};

#pragma unroll 1
    for (int ch = 0; ch < CHUNKS; ++ch) {
        __syncthreads();   // buffer ch&1 staged; buffer (ch+1)&1 free

        // P fragments (A operand) from current buffer
        half8 pf16[4];
#pragma unroll
        for (int c = 0; c < 4; ++c) {
            int dblk = c * 4 + q;
            int col  = cb + n;
            int dbs  = (dblk & 8) | ((dblk ^ col) & 7);
            pf16[c] = *(const half8*)&Pst[ch & 1][col * 128 + dbs * 8];
        }

        f32x4 acc[2] = {{0.f,0.f,0.f,0.f},{0.f,0.f,0.f,0.f}};
#pragma unroll
        for (int c = 0; c < 4; ++c)
#pragma unroll
            for (int rf = 0; rf < 2; ++rf)
                acc[rf] = __builtin_amdgcn_mfma_f32_16x16x32_f16(pf16[c], vh[rf][c], acc[rf], 0, 0, 0);

        // stage next chunk into the other buffer (pf loaded a full chunk ago)
        if (ch < CHUNKS - 1) {
            half8 hv;
            hv[0] = (_Float16)pf0.x; hv[1] = (_Float16)pf0.y;
            hv[2] = (_Float16)pf0.z; hv[3] = (_Float16)pf0.w;
            hv[4] = (_Float16)pf1.x; hv[5] = (_Float16)pf1.y;
            hv[6] = (_Float16)pf1.z; hv[7] = (_Float16)pf1.w;
            *(half8*)&Pst[(ch + 1) & 1][scol * 128 + sdbs * 8] = hv;
        }
        if (ch < CHUNKS - 2) {
            const float* pp = P + (size_t)((ch + 2) * 64 + scol) * 128 + sdb * 8;
            pf0 = *(const float4*)(pp);
            pf1 = *(const float4*)(pp + 4);
        }

        // ---- epilogue: softmax over m (4 in-lane + xor16), logsumexp partials ----
        const int cbase = ch * 8 + colq * 2;
        const int cA    = cbase + (q >> 1);
#pragma unroll
        for (int rf = 0; rf < 2; ++rf) {
            float s0 = acc[rf][0], s1 = acc[rf][1], s2 = acc[rf][2], s3 = acc[rf][3];
            float e0 = __expf(LT * s0), e1 = __expf(LT * s1);
            float e2 = __expf(LT * s2), e3 = __expf(LT * s3);
            float es = (e0 + e1) + (e2 + e3);
            float ss = fmaf(e0, s0, fmaf(e1, s1, fmaf(e2, s2, e3 * s3)));
            es += swz16(es);
            ss += swz16(ss);
            float simc = __fdividef(ss, es);
            dn[rf] += __expf(LT * simc);
            int rowloc = rg * 32 + rf * 16 + n;
            if (cA == ((rowbase + rowloc) & 255) && (q & 1) == 0)
                sh_simpos[rowloc] = simc;
        }
    }

    // ---- fold per-lane denominators (q pairs duplicate concepts -> x0.5) ----
#pragma unroll
    for (int rf = 0; rf < 2; ++rf) {
        float t = dn[rf];
        t += swz16(t);
        t += __shfl_xor(t, 32);
        if (q == 0)
            atomicAdd(&sh_denom[rg * 32 + rf * 16 + n], 0.5f * t);
    }
    __syncthreads();

    // ---- in-block loss over 128 rows, then one global atomic per block ----
    float s = 0.f, cc = 0.f;
    if (tid < 128) {
        int row = rowbase + tid;
        float lp = logf(sh_denom[tid] + 1e-8f) - LT * (sh_simpos[tid] + 0.05f);
        float mk = (labels[row] == 1) ? 1.0f : 0.0f;
        s = lp * mk;
        cc = mk;
    }
#pragma unroll
    for (int off = 32; off >= 1; off >>= 1) {
        s  += __shfl_down(s, off);
        cc += __shfl_down(cc, off);
    }
    if (lane == 0) { sh_red[w] = s; sh_red[16 + w] = cc; }
    __syncthreads();
    if (tid == 0) {
        s = 0.f; cc = 0.f;
#pragma unroll
        for (int i = 0; i < 16; ++i) { s += sh_red[i]; cc += sh_red[16 + i]; }
        atomicAdd(&gsum[0], s);
        atomicAdd(&gsum[1], cc);
        __threadfence();
        int g = __hip_atomic_fetch_add(gcnt, 1,
                                       __ATOMIC_ACQ_REL, __HIP_MEMORY_SCOPE_AGENT);
        if (g == 255) {   // last of 256 blocks finalizes
            __threadfence();
            float ts = __hip_atomic_load(&gsum[0], __ATOMIC_RELAXED, __HIP_MEMORY_SCOPE_AGENT);
            float tc = __hip_atomic_load(&gsum[1], __ATOMIC_RELAXED, __HIP_MEMORY_SCOPE_AGENT);
            out[0] = (tc > 0.0f) ? (ts / tc) : ts;
        }
    }
}

extern "C" void kernel_launch(void* const* d_in, const int* in_sizes, int n_in,
                              void* d_out, int out_size, void* d_ws, size_t ws_size,
                              hipStream_t stream)
{
    const float* V      = (const float*)d_in[0];
    const int*   labels = (const int*)d_in[1];
    const float* P      = (const float*)d_in[2];
    float* out = (float*)d_out;
    int*   ws  = (int*)d_ws;

    hipMemsetAsync(ws, 0, 16, stream);   // gcnt + gsum
    mpcl_main<<<256, 1024, 0, stream>>>(V, labels, P, ws, out);
}

// Round 5
// 110.433 us; speedup vs baseline: 1.6416x; 1.0458x over previous
//
#include <hip/hip_runtime.h>

// B=128, K=256, M=8, D=128 ; rows = B*K = 32768 flattened (b,k)
#define NROWS 32768
#define LT 20.0f        // lambda == gamma == 20
#define CHUNKS 16       // 16 chunks x 128 cols = all 2048 prototype columns

typedef _Float16 half8 __attribute__((ext_vector_type(8)));
typedef float    f32x4 __attribute__((ext_vector_type(4)));

__device__ __forceinline__ float swz16(float x) {
    // xor lane^16 within 32-lane halves (BitMode: xor=16, and=0x1F)
    return __int_as_float(__builtin_amdgcn_ds_swizzle(__float_as_int(x), 0x401F));
}

// async global->LDS, 16B per lane; lds base must be wave-uniform
#define GLD16(gp, lp) __builtin_amdgcn_global_load_lds( \
    (const __attribute__((address_space(1))) void*)(gp), \
    (__attribute__((address_space(3))) void*)(lp), 16, 0, 0)

// ---- prep: f32 P -> f16, permuted+swizzled so a linear lane-ordered copy lands
// the main kernel's LDS layout: slot(chunk ch, col, dbs) with
// dbs = (dblk&8) | ((dblk ^ key(col)) & 7), key(col) = (col&3)|((col&8)>>1)
__global__ __launch_bounds__(256)
void mpcl_prep(const float* __restrict__ P, _Float16* __restrict__ Pw)
{
    int id   = blockIdx.x * 256 + threadIdx.x;   // 0..32767
    int gcol = id >> 4;                          // 0..2047 P row (concept*8+m)
    int dblk = id & 15;                          // d/8
    int ch   = gcol >> 7;
    int col  = gcol & 127;
    int key  = (col & 3) | ((col & 8) >> 1);
    int dbs  = (dblk & 8) | ((dblk ^ key) & 7);
    const float* src = P + (size_t)gcol * 128 + dblk * 8;
    float4 a = *(const float4*)src;
    float4 b = *(const float4*)(src + 4);
    half8 hv;
    hv[0] = (_Float16)a.x; hv[1] = (_Float16)a.y;
    hv[2] = (_Float16)a.z; hv[3] = (_Float16)a.w;
    hv[4] = (_Float16)b.x; hv[5] = (_Float16)b.y;
    hv[6] = (_Float16)b.z; hv[7] = (_Float16)b.w;
    *(half8*)&Pw[((size_t)ch * 2048 + col * 16 + dbs) * 8] = hv;
}

// Grid: 256 blocks x 1024 thr (16 waves). Block owns 128 rows x all 2048 cols.
// wave w: rg=w>>2 -> 32 rows; colq=w&3 -> 4 concepts (32 cols) per 128-col chunk.
// MFMA pair trick: A1 = protos 0-3 of 4 concepts (16 rows), A2 = protos 4-7.
// C-layout lane(q,n): rows q*4+reg -> concept q, proto reg; col n = V row.
// => all 8 protos of one concept live in acc1+acc2 of one lane: no swizzle.
__global__ __launch_bounds__(1024)
void mpcl_main(const float* __restrict__ V,        // (32768, 128)
               const int*   __restrict__ labels,   // (32768)
               const _Float16* __restrict__ Pw,    // packed P (prep)
               int* __restrict__ ws,               // [0]=gcnt, [2..3]=gsum
               float* __restrict__ out)
{
    __shared__ __align__(16) _Float16 Pst[2][2048 * 8];   // 2 x 32 KB
    __shared__ float sh_denom[128];
    __shared__ float sh_simpos[128];
    __shared__ float sh_red[32];

    int*   gcnt = ws;
    float* gsum = (float*)(ws + 2);

    const int tid  = threadIdx.x;
    const int lane = tid & 63;
    const int w    = tid >> 6;
    const int rg   = w >> 2;          // 0..3 -> 32-row group
    const int colq = w & 3;           // 0..3 -> 4-concept group per chunk
    const int n    = lane & 15;
    const int q    = lane >> 4;
    const int rowbase = blockIdx.x * 128;

    if (tid < 128) { sh_denom[tid] = 0.0f; sh_simpos[tid] = 0.0f; }

    // ---- V fragments (B operand), f16, register-resident ----
    half8 vh[2][4];
#pragma unroll
    for (int rf = 0; rf < 2; ++rf) {
        const float* vr = V + (size_t)(rowbase + rg * 32 + rf * 16 + n) * 128 + q * 8;
#pragma unroll
        for (int c = 0; c < 4; ++c) {
            float4 x0 = *(const float4*)(vr + c * 32);
            float4 x1 = *(const float4*)(vr + c * 32 + 4);
            vh[rf][c][0] = (_Float16)x0.x; vh[rf][c][1] = (_Float16)x0.y;
            vh[rf][c][2] = (_Float16)x0.z; vh[rf][c][3] = (_Float16)x0.w;
            vh[rf][c][4] = (_Float16)x1.x; vh[rf][c][5] = (_Float16)x1.y;
            vh[rf][c][6] = (_Float16)x1.z; vh[rf][c][7] = (_Float16)x1.w;
        }
    }

    // ---- A-fragment LDS offsets (halves), constant across chunks ----
    // col1 = colq*32 + (n>>2)*8 + (n&3): concept n>>2, proto n&3 ; col2=col1+4
    // key(col1)=key(col2)=n&7 ; dblk = c*4+q
    const int col1 = colq * 32 + ((n >> 2) << 3) + (n & 3);
    int off1[4];
#pragma unroll
    for (int c = 0; c < 4; ++c) {
        int dblk = c * 4 + q;
        int dbs  = (dblk & 8) | ((dblk ^ (n & 7)) & 7);
        off1[c]  = (col1 * 16 + dbs) * 8;
    }

    // ---- staging: each wave issues 2 async 16B/lane copies per chunk ----
    const _Float16* gbase = Pw + (size_t)(w * 128 + lane) * 8;
    _Float16* l0 = &Pst[0][(w * 128) * 8];    // wave-uniform LDS bases
    _Float16* l1 = &Pst[1][(w * 128) * 8];

    GLD16(gbase,       l0);        // chunk 0
    GLD16(gbase + 512, l0 + 512);

    const int rowk0 = (rowbase + rg * 32 + n) & 255;        // positive concept, rf=0
    const int rowk1 = (rowbase + rg * 32 + 16 + n) & 255;   // rf=1

    float dn[2] = {0.f, 0.f};

#pragma unroll 1
    for (int ch = 0; ch < CHUNKS; ++ch) {
        __syncthreads();   // chunk ch staged (vmcnt drained at barrier)

        if (ch < CHUNKS - 1) {   // fire next chunk's loads; they land by next barrier
            const _Float16* g = gbase + (size_t)(ch + 1) * 16384;
            _Float16* lnx = (ch & 1) ? l0 : l1;
            GLD16(g,       lnx);
            GLD16(g + 512, lnx + 512);
        }

        const _Float16* base = (ch & 1) ? &Pst[1][0] : &Pst[0][0];

        f32x4 acc1[2] = {{0.f,0.f,0.f,0.f},{0.f,0.f,0.f,0.f}};
        f32x4 acc2[2] = {{0.f,0.f,0.f,0.f},{0.f,0.f,0.f,0.f}};
#pragma unroll
        for (int c = 0; c < 4; ++c) {
            half8 a1 = *(const half8*)&base[off1[c]];
            half8 a2 = *(const half8*)&base[off1[c] + 512];   // col+4 -> +4*16*8 halves
            acc1[0] = __builtin_amdgcn_mfma_f32_16x16x32_f16(a1, vh[0][c], acc1[0], 0, 0, 0);
            acc1[1] = __builtin_amdgcn_mfma_f32_16x16x32_f16(a1, vh[1][c], acc1[1], 0, 0, 0);
            acc2[0] = __builtin_amdgcn_mfma_f32_16x16x32_f16(a2, vh[0][c], acc2[0], 0, 0, 0);
            acc2[1] = __builtin_amdgcn_mfma_f32_16x16x32_f16(a2, vh[1][c], acc2[1], 0, 0, 0);
        }

        // ---- epilogue: full softmax-over-8 in-lane, no cross-lane ops ----
        const int cA = ch * 16 + colq * 4 + q;   // this lane's concept
#pragma unroll
        for (int rf = 0; rf < 2; ++rf) {
            float x0 = acc1[rf][0], x1 = acc1[rf][1], x2 = acc1[rf][2], x3 = acc1[rf][3];
            float x4 = acc2[rf][0], x5 = acc2[rf][1], x6 = acc2[rf][2], x7 = acc2[rf][3];
            float e0 = __expf(LT * x0), e1 = __expf(LT * x1);
            float e2 = __expf(LT * x2), e3 = __expf(LT * x3);
            float e4 = __expf(LT * x4), e5 = __expf(LT * x5);
            float e6 = __expf(LT * x6), e7 = __expf(LT * x7);
            float es = ((e0 + e1) + (e2 + e3)) + ((e4 + e5) + (e6 + e7));
            float ss = fmaf(e0, x0, fmaf(e1, x1, fmaf(e2, x2, e3 * x3)))
                     + fmaf(e4, x4, fmaf(e5, x5, fmaf(e6, x6, e7 * x7)));
            float simc = __fdividef(ss, es);
            dn[rf] += __expf(LT * simc);
            if (cA == (rf ? rowk1 : rowk0))
                sh_simpos[rg * 32 + rf * 16 + n] = simc;   // unique writer per row
        }
    }

    // ---- fold denominators over the 4 q-groups (distinct concepts) ----
#pragma unroll
    for (int rf = 0; rf < 2; ++rf) {
        float t = dn[rf];
        t += swz16(t);
        t += __shfl_xor(t, 32);
        if (lane < 16)
            atomicAdd(&sh_denom[rg * 32 + rf * 16 + n], t);
    }
    __syncthreads();

    // ---- in-block loss over 128 rows, then one global atomic per block ----
    float s = 0.f, cc = 0.f;
    if (tid < 128) {
        int row = rowbase + tid;
        float lp = logf(sh_denom[tid] + 1e-8f) - LT * (sh_simpos[tid] + 0.05f);
        float mk = (labels[row] == 1) ? 1.0f : 0.0f;
        s = lp * mk;
        cc = mk;
    }
#pragma unroll
    for (int off = 32; off >= 1; off >>= 1) {
        s  += __shfl_down(s, off);
        cc += __shfl_down(cc, off);
    }
    if (lane == 0) { sh_red[w] = s; sh_red[16 + w] = cc; }
    __syncthreads();
    if (tid == 0) {
        s = 0.f; cc = 0.f;
#pragma unroll
        for (int i = 0; i < 16; ++i) { s += sh_red[i]; cc += sh_red[16 + i]; }
        atomicAdd(&gsum[0], s);
        atomicAdd(&gsum[1], cc);
        __threadfence();
        int g = __hip_atomic_fetch_add(gcnt, 1,
                                       __ATOMIC_ACQ_REL, __HIP_MEMORY_SCOPE_AGENT);
        if (g == 255) {   // last of 256 blocks finalizes
            __threadfence();
            float ts = __hip_atomic_load(&gsum[0], __ATOMIC_RELAXED, __HIP_MEMORY_SCOPE_AGENT);
            float tc = __hip_atomic_load(&gsum[1], __ATOMIC_RELAXED, __HIP_MEMORY_SCOPE_AGENT);
            out[0] = (tc > 0.0f) ? (ts / tc) : ts;
        }
    }
}

extern "C" void kernel_launch(void* const* d_in, const int* in_sizes, int n_in,
                              void* d_out, int out_size, void* d_ws, size_t ws_size,
                              hipStream_t stream)
{
    const float* V      = (const float*)d_in[0];
    const int*   labels = (const int*)d_in[1];
    const float* P      = (const float*)d_in[2];
    float* out = (float*)d_out;
    int*   ws  = (int*)d_ws;
    _Float16* Pw = (_Float16*)((char*)d_ws + 512);   // 512 KB packed P

    hipMemsetAsync(ws, 0, 16, stream);               // gcnt + gsum
    mpcl_prep<<<128, 256, 0, stream>>>(P, Pw);
    mpcl_main<<<256, 1024, 0, stream>>>(V, labels, Pw, ws, out);
}